// Round 7
// baseline (418.281 us; speedup 1.0000x reference)
//
#include <hip/hip_runtime.h>
#include <stdint.h>

typedef _Float16 f16;
typedef _Float16 f16x4 __attribute__((ext_vector_type(4)));
typedef _Float16 f16x8 __attribute__((ext_vector_type(8)));
typedef float floatx4 __attribute__((ext_vector_type(4)));
typedef float floatx16 __attribute__((ext_vector_type(16)));

#define B_ROWS 4096
#define D_IN   768
#define H_DIM  16384
#define TOPK_N 32
#define NC     40    // target candidate count (superset of exact top-32)
#define NCAP   192   // hard cap on candidates per row

#define BM 128
#define BN 256
#define BK 32
#define NKT (D_IN / BK)   // 24 K-tiles

typedef __attribute__((address_space(1))) const unsigned int g_uint;
typedef __attribute__((address_space(3))) unsigned int l_uint;

__device__ __forceinline__ void gload_lds16(const void* g, void* l) {
    __builtin_amdgcn_global_load_lds((g_uint*)(uintptr_t)g,
                                     (l_uint*)(uint32_t)(uintptr_t)l,
                                     16, 0, 0);
}

// ---------------- split x -> f16 ----------------
__global__ __launch_bounds__(256) void split_x(const float* __restrict__ x,
                                               f16* __restrict__ xhi) {
    const int i = blockIdx.x * 256 + threadIdx.x;
    const float4 q = ((const float4*)x)[i];
    f16x4 h;
    h[0] = (f16)q.x; h[1] = (f16)q.y; h[2] = (f16)q.z; h[3] = (f16)q.w;
    ((f16x4*)xhi)[i] = h;
}

// ---------------- transpose + hi/lo split of W_enc ----------------
// W [768][16384] f32  ->  whiT/wloT [16384][768] f16 (k contiguous)
__global__ __launch_bounds__(256) void split_transpose_w(const float* __restrict__ W,
                                                         f16* __restrict__ whiT,
                                                         f16* __restrict__ wloT) {
    __shared__ float tile[64][65];
    const int kb = blockIdx.x;      // 0..11
    const int nb = blockIdx.y;      // 0..255
    const int t  = threadIdx.x;
    const int col = t & 63;
    const int r4  = t >> 6;
#pragma unroll
    for (int p = 0; p < 16; ++p) {
        const int kr = p * 4 + r4;
        tile[kr][col] = W[(size_t)(kb * 64 + kr) * H_DIM + nb * 64 + col];
    }
    __syncthreads();
    const int n  = t >> 2;
    const int kq = (t & 3) * 16;
    f16x8 h0, h1, l0, l1;
#pragma unroll
    for (int j = 0; j < 8; ++j) {
        const float v0 = tile[kq + j][n];
        const f16 ha = (f16)v0; h0[j] = ha; l0[j] = (f16)(v0 - (float)ha);
        const float v1 = tile[kq + 8 + j][n];
        const f16 hb = (f16)v1; h1[j] = hb; l1[j] = (f16)(v1 - (float)hb);
    }
    const size_t base = (size_t)(nb * 64 + n) * D_IN + kb * 64 + kq;
    *(f16x8*)&whiT[base]     = h0;
    *(f16x8*)&whiT[base + 8] = h1;
    *(f16x8*)&wloT[base]     = l0;
    *(f16x8*)&wloT[base + 8] = l1;
}

// ---------------- encode GEMM: 128x256, BK=32, classic dbuf, 2 blocks/CU ----------
// LDS: 2 buf x (A[128][32] + B[256][32]) f16 = 48 KiB -> 2 blocks/CU by LDS;
// __launch_bounds__(512,4) caps VGPR at 128 -> 16 waves/CU -> cross-block overlap
// hides the vmcnt(0) drain at each __syncthreads (the R5 1-block/CU stall).
// Swizzle: rows are 64 B, bank = (row&1)*16 + slot*4 + word, so XOR the 16B slot
// with (row>>1)&3 (covers all 8 parity x slot groups -> 2-way, free). Applied
// both sides: pre-swizzled global source + swizzled ds_read; LDS dest linear.
// MFMA 32x32x16_f16 mapping HW-validated in R6 (absmax 0.0078 passed).
#define STAGE(buf, kt) do {                                                         \
    const int ko_ = (kt) * BK;                                                      \
    gload_lds16(xhi  + aoff  + ko_, sA + (buf) * 4096 + tid * 8);                   \
    gload_lds16(whiT + boff0 + ko_, sB + (buf) * 8192 + tid * 8);                   \
    gload_lds16(whiT + boff1 + ko_, sB + (buf) * 8192 + 4096 + tid * 8);            \
} while (0)

__global__ __launch_bounds__(512, 4) void encode_gemm(const f16* __restrict__ xhi,
                                                      const f16* __restrict__ whiT,
                                                      const float* __restrict__ b_enc,
                                                      float* __restrict__ preact) {
    extern __shared__ __align__(16) f16 smem[];
    f16* sA = smem;          // 2 * 128*32 f16 = 16 KiB
    f16* sB = smem + 8192;   // 2 * 256*32 f16 = 32 KiB
    const int tid = threadIdx.x;
    const int bid = blockIdx.x;
    const int swzb = (bid & 7) * 256 + (bid >> 3);   // XCD swizzle, nwg=2048 % 8 == 0
    const int m0 = (swzb >> 6) * BM;                 // 32 m-blocks
    const int n0 = (swzb & 63) * BN;                 // 64 n-blocks
    const int lane = tid & 63;
    const int wid  = tid >> 6;
    const int wr = wid >> 2;                         // 0..1 (64 rows each)
    const int wc = wid & 3;                          // 0..3 (64 cols each)
    const int lr = lane & 31;
    const int lh = lane >> 5;                        // k-chunk 0..1
    const int xr3 = (lr >> 1) & 3;                   // reader slot-XOR ((row>>1)&3)

    // staging: thread covers row srow = tid>>2, 16B chunk c = tid&3,
    // source slot pre-swizzled by ((row>>1)&3) = ((tid>>3)&3)
    const int srow = tid >> 2;
    const int sw = ((tid & 3) ^ ((tid >> 3) & 3)) << 3;
    const int aoff  = (m0 + srow) * D_IN + sw;
    const int boff0 = (n0 + srow) * D_IN + sw;
    const int boff1 = (n0 + 128 + srow) * D_IN + sw;

    floatx16 acc[2][2];
#pragma unroll
    for (int i = 0; i < 2; ++i)
#pragma unroll
        for (int j = 0; j < 2; ++j)
#pragma unroll
            for (int r = 0; r < 16; ++r) acc[i][j][r] = 0.f;

    STAGE(0, 0);
    for (int t = 0; t < NKT; ++t) {
        __syncthreads();                 // drains vmcnt(0)+lgkmcnt(0): tile t landed,
                                         // iter t-1's ds_reads complete in all waves
        if (t + 1 < NKT) STAGE((t + 1) & 1, t + 1);
        const int bA = (t & 1) * 4096;
        const int bB = (t & 1) * 8192;
#pragma unroll
        for (int ks = 0; ks < 2; ++ks) {             // 2 k-steps of 16
            const int sx = ((ks * 2 + lh) ^ xr3) * 8;
            f16x8 af0, af1, bf0, bf1;
            af0 = *(const f16x8*)(sA + bA + (wr * 64 + lr) * 32 + sx);
            af1 = *(const f16x8*)(sA + bA + (wr * 64 + 32 + lr) * 32 + sx);
            bf0 = *(const f16x8*)(sB + bB + (wc * 64 + lr) * 32 + sx);
            bf1 = *(const f16x8*)(sB + bB + (wc * 64 + 32 + lr) * 32 + sx);
            acc[0][0] = __builtin_amdgcn_mfma_f32_32x32x16_f16(af0, bf0, acc[0][0], 0, 0, 0);
            acc[0][1] = __builtin_amdgcn_mfma_f32_32x32x16_f16(af0, bf1, acc[0][1], 0, 0, 0);
            acc[1][0] = __builtin_amdgcn_mfma_f32_32x32x16_f16(af1, bf0, acc[1][0], 0, 0, 0);
            acc[1][1] = __builtin_amdgcn_mfma_f32_32x32x16_f16(af1, bf1, acc[1][1], 0, 0, 0);
        }
    }

    // epilogue: 32x32 C/D layout (col = lane&31, row = (r&3)+8*(r>>2)+4*lh); bias, fp32
#pragma unroll
    for (int nt = 0; nt < 2; ++nt) {
        const int col = n0 + wc * 64 + nt * 32 + lr;
        const float bias = b_enc[col];
#pragma unroll
        for (int mt = 0; mt < 2; ++mt) {
            const int rowb = m0 + wr * 64 + mt * 32 + 4 * lh;
#pragma unroll
            for (int r = 0; r < 16; ++r) {
                const int row = rowb + (r & 3) + 8 * (r >> 2);
                preact[(size_t)row * H_DIM + col] = acc[mt][nt][r] + bias;
            }
        }
    }
}

// ---------------- candidate selection: single-level linear-bin select ----------------
__global__ __launch_bounds__(256) void topk_approx(const float* __restrict__ preact,
                                                   int* __restrict__ cand,
                                                   int* __restrict__ ccnt) {
    const int row = blockIdx.x;
    const int t   = threadIdx.x;
    const float* pr = preact + (size_t)row * H_DIM;
    float vr[64];
    float m = 0.f;
#pragma unroll
    for (int i = 0; i < 16; ++i) {
        const float4 q = ((const float4*)pr)[t + 256 * i];
        vr[4 * i + 0] = q.x; vr[4 * i + 1] = q.y;
        vr[4 * i + 2] = q.z; vr[4 * i + 3] = q.w;
        m = fmaxf(m, fmaxf(fmaxf(q.x, q.y), fmaxf(q.z, q.w)));
    }
#pragma unroll
    for (int off = 32; off > 0; off >>= 1) m = fmaxf(m, __shfl_down(m, off));

    __shared__ float wmax[4];
    __shared__ unsigned hist[256];
    __shared__ unsigned sbin_s, out_cnt;
    if ((t & 63) == 0) wmax[t >> 6] = m;
    hist[t] = 0u;
    if (t == 0) { sbin_s = 0u; out_cnt = 0u; }
    __syncthreads();
    const float M = fmaxf(fmaxf(wmax[0], wmax[1]), fmaxf(wmax[2], wmax[3]));
    int* crow = cand + row * NCAP;

    if (M > 0.f) {
        const float scale = 256.0f / M;
#pragma unroll
        for (int e = 0; e < 64; ++e) {
            const float v = vr[e];
            if (v > 0.f) {
                int b = (int)(v * scale); b = b > 255 ? 255 : b;
                atomicAdd(&hist[b], 1u);
            }
        }
        __syncthreads();
        unsigned sval = hist[t];
        for (int off = 1; off < 256; off <<= 1) {
            const unsigned add = (t + off < 256) ? hist[t + off] : 0u;
            __syncthreads();
            sval += add;
            hist[t] = sval;
            __syncthreads();
        }
        const unsigned above = (t < 255) ? hist[t + 1] : 0u;
        if (sval >= NC && above < NC) sbin_s = (unsigned)t;
        __syncthreads();
        const int sbin = (int)sbin_s;
#pragma unroll
        for (int e = 0; e < 64; ++e) {
            const float v = vr[e];
            if (v > 0.f) {
                int b = (int)(v * scale); b = b > 255 ? 255 : b;
                if (b >= sbin) {
                    const unsigned p = atomicAdd(&out_cnt, 1u);
                    if (p < NCAP) crow[p] = 4 * t + 1024 * (e >> 2) + (e & 3);
                }
            }
        }
        __syncthreads();
    }
    if (t == 0) ccnt[row] = (int)(out_cnt < NCAP ? out_cnt : NCAP);
}

// ---------------- exact fp32 refinement of candidates + hidden write ----------------
__global__ __launch_bounds__(256) void refine_kernel(const float* __restrict__ x,
                                                     const f16* __restrict__ whiT,
                                                     const f16* __restrict__ wloT,
                                                     const float* __restrict__ b_enc,
                                                     const int* __restrict__ cand,
                                                     const int* __restrict__ ccnt,
                                                     float* __restrict__ hidden,
                                                     float* __restrict__ topv,
                                                     int* __restrict__ topi) {
    const int row  = blockIdx.x;
    const int t    = threadIdx.x;
    const int lane = t & 63;
    const int wave = t >> 6;
    __shared__ float xr[D_IN];
    __shared__ float cv[NCAP];
    __shared__ int   ci[NCAP];
    __shared__ float selv[TOPK_N];
    __shared__ int   seli[TOPK_N];

    const int cnt = ccnt[row];
    if (t < NCAP) ci[t] = (t < cnt) ? cand[row * NCAP + t] : -1;
    if (t < TOPK_N) { selv[t] = -3.0e38f; seli[t] = -1; }
#pragma unroll
    for (int j = 0; j < 3; ++j)
        xr[t + 256 * j] = x[(size_t)row * D_IN + t + 256 * j];
    __syncthreads();

    for (int c = wave; c < cnt; c += 4) {
        const int n = ci[c];
        float sum = 0.f;
        const f16* wh = whiT + (size_t)n * D_IN;
        const f16* wl = wloT + (size_t)n * D_IN;
#pragma unroll
        for (int j = 0; j < 12; ++j) {
            const int k = lane + 64 * j;
            sum += xr[k] * ((float)wh[k] + (float)wl[k]);
        }
#pragma unroll
        for (int off = 32; off > 0; off >>= 1) sum += __shfl_down(sum, off);
        if (lane == 0) cv[c] = sum + b_enc[n];
    }
    __syncthreads();

    if (t < cnt) {
        const float vi = cv[t];
        const int   ii = ci[t];
        int rank = 0;
        for (int j = 0; j < cnt; ++j) {
            const float vj = cv[j];
            rank += (vj > vi) || (vj == vi && ci[j] < ii);
        }
        if (rank < TOPK_N) { selv[rank] = vi; seli[rank] = ii; }
    }
    __syncthreads();

    float* hrow = hidden + (size_t)row * H_DIM;
    const float4 z = {0.f, 0.f, 0.f, 0.f};
#pragma unroll
    for (int i = 0; i < 16; ++i) ((float4*)hrow)[t + 256 * i] = z;
    __syncthreads();
    if (t < TOPK_N) {
        const int n = seli[t];
        float v = selv[t];
        v = (n >= 0) ? fmaxf(v, 0.f) : 0.f;
        topv[row * TOPK_N + t] = v;
        topi[row * TOPK_N + t] = (n >= 0) ? n : 0;
        if (v > 0.f) hrow[n] = v;
    }
}

// ---------------- sparse decode: out = relu(hidden_sparse @ W_dec + b_dec) ----------------
__global__ __launch_bounds__(256) void decode_kernel(const float* __restrict__ topv,
                                                     const int* __restrict__ topi,
                                                     const float* __restrict__ Wdec,
                                                     const float* __restrict__ bdec,
                                                     float* __restrict__ out) {
    const int row = blockIdx.x;
    const int t   = threadIdx.x;
    __shared__ float sv[TOPK_N];
    __shared__ int   si[TOPK_N];
    if (t < TOPK_N) { sv[t] = topv[row * TOPK_N + t]; si[t] = topi[row * TOPK_N + t]; }
    __syncthreads();
    float a0 = 0.f, a1 = 0.f, a2 = 0.f;
#pragma unroll 4
    for (int j = 0; j < TOPK_N; ++j) {
        const float v = sv[j];
        const float* wr = Wdec + (size_t)si[j] * D_IN;
        a0 += v * wr[t];
        a1 += v * wr[t + 256];
        a2 += v * wr[t + 512];
    }
    float* orow = out + (size_t)row * D_IN;
    orow[t]       = fmaxf(a0 + bdec[t], 0.f);
    orow[t + 256] = fmaxf(a1 + bdec[t + 256], 0.f);
    orow[t + 512] = fmaxf(a2 + bdec[t + 512], 0.f);
}

extern "C" void kernel_launch(void* const* d_in, const int* in_sizes, int n_in,
                              void* d_out, int out_size, void* d_ws, size_t ws_size,
                              hipStream_t stream) {
    const float* x     = (const float*)d_in[0];
    const float* W_enc = (const float*)d_in[1];
    const float* b_enc = (const float*)d_in[2];
    const float* W_dec = (const float*)d_in[3];
    const float* b_dec = (const float*)d_in[4];

    float* out    = (float*)d_out;
    float* hidden = out + (size_t)B_ROWS * D_IN;
    float* preact = hidden + (size_t)B_ROWS * H_DIM;

    uint8_t* ws = (uint8_t*)d_ws;
    size_t off = 0;
    f16* xhi  = (f16*)(ws + off); off += (size_t)B_ROWS * D_IN * 2;
    f16* whiT = (f16*)(ws + off); off += (size_t)H_DIM * D_IN * 2;
    f16* wloT = (f16*)(ws + off); off += (size_t)H_DIM * D_IN * 2;
    int*   cand = (int*)(ws + off);  off += (size_t)B_ROWS * NCAP * 4;
    int*   ccnt = (int*)(ws + off);  off += (size_t)B_ROWS * 4;
    float* topv = (float*)(ws + off); off += (size_t)B_ROWS * TOPK_N * 4;
    int*   topi = (int*)(ws + off);  off += (size_t)B_ROWS * TOPK_N * 4;
    if (off > ws_size) return;  // insufficient workspace -> fail visibly

    hipFuncSetAttribute(reinterpret_cast<const void*>(encode_gemm),
                        hipFuncAttributeMaxDynamicSharedMemorySize, 49152);

    split_x<<<(B_ROWS * D_IN / 4) / 256, 256, 0, stream>>>(x, xhi);
    dim3 gw(D_IN / 64, H_DIM / 64);
    split_transpose_w<<<gw, 256, 0, stream>>>(W_enc, whiT, wloT);
    encode_gemm<<<(B_ROWS / BM) * (H_DIM / BN), 512, 49152, stream>>>(xhi, whiT, b_enc, preact);
    topk_approx<<<B_ROWS, 256, 0, stream>>>(preact, cand, ccnt);
    refine_kernel<<<B_ROWS, 256, 0, stream>>>(x, whiT, wloT, b_enc, cand, ccnt, hidden, topv, topi);
    decode_kernel<<<B_ROWS, 256, 0, stream>>>(topv, topi, W_dec, b_dec, out);
}

// Round 8
// 406.107 us; speedup vs baseline: 1.0300x; 1.0300x over previous
//
#include <hip/hip_runtime.h>
#include <stdint.h>

typedef _Float16 f16;
typedef _Float16 f16x2 __attribute__((ext_vector_type(2)));
typedef _Float16 f16x4 __attribute__((ext_vector_type(4)));
typedef _Float16 f16x8 __attribute__((ext_vector_type(8)));
typedef float floatx4 __attribute__((ext_vector_type(4)));

#define B_ROWS 4096
#define D_IN   768
#define H_DIM  16384
#define TOPK_N 32
#define NC     40    // target candidate count (superset of exact top-32)
#define NCAP   192   // hard cap on candidates per row

#define BM 256
#define BN 256
#define BK 64
#define NKT (D_IN / BK)   // 12 K-tiles

typedef __attribute__((address_space(1))) const unsigned int g_uint;
typedef __attribute__((address_space(3))) unsigned int l_uint;

__device__ __forceinline__ void gload_lds16(const void* g, void* l) {
    __builtin_amdgcn_global_load_lds((g_uint*)(uintptr_t)g,
                                     (l_uint*)(uint32_t)(uintptr_t)l,
                                     16, 0, 0);
}

// ---------------- split x -> f16 ----------------
__global__ __launch_bounds__(256) void split_x(const float* __restrict__ x,
                                               f16* __restrict__ xhi) {
    const int i = blockIdx.x * 256 + threadIdx.x;
    const float4 q = ((const float4*)x)[i];
    f16x4 h;
    h[0] = (f16)q.x; h[1] = (f16)q.y; h[2] = (f16)q.z; h[3] = (f16)q.w;
    ((f16x4*)xhi)[i] = h;
}

// ---------------- transpose + hi/lo split of W_enc ----------------
// W [768][16384] f32  ->  whiT/wloT [16384][768] f16 (k contiguous)
__global__ __launch_bounds__(256) void split_transpose_w(const float* __restrict__ W,
                                                         f16* __restrict__ whiT,
                                                         f16* __restrict__ wloT) {
    __shared__ float tile[64][65];
    const int kb = blockIdx.x;      // 0..11
    const int nb = blockIdx.y;      // 0..255
    const int t  = threadIdx.x;
    const int col = t & 63;
    const int r4  = t >> 6;
#pragma unroll
    for (int p = 0; p < 16; ++p) {
        const int kr = p * 4 + r4;
        tile[kr][col] = W[(size_t)(kb * 64 + kr) * H_DIM + nb * 64 + col];
    }
    __syncthreads();
    const int n  = t >> 2;
    const int kq = (t & 3) * 16;
    f16x8 h0, h1, l0, l1;
#pragma unroll
    for (int j = 0; j < 8; ++j) {
        const float v0 = tile[kq + j][n];
        const f16 ha = (f16)v0; h0[j] = ha; l0[j] = (f16)(v0 - (float)ha);
        const float v1 = tile[kq + 8 + j][n];
        const f16 hb = (f16)v1; h1[j] = hb; l1[j] = (f16)(v1 - (float)hb);
    }
    const size_t base = (size_t)(nb * 64 + n) * D_IN + kb * 64 + kq;
    *(f16x8*)&whiT[base]     = h0;
    *(f16x8*)&whiT[base + 8] = h1;
    *(f16x8*)&wloT[base]     = l0;
    *(f16x8*)&wloT[base + 8] = l1;
}

// ---------------- encode GEMM: 256x256, BK=64, classic dbuf (R5-proven) ----------
// n-major XCD swizzle: XCD x owns n-panels [8x, 8x+8) x all 16 m-panels, so its
// B working set is 8*256 rows * 768 * 2B = 3.1 MB -> L2-resident (4 MB/XCD).
#define STAGE(buf, kt) do {                                                        \
    const int ko_ = (kt) * BK;                                                     \
    _Pragma("unroll")                                                              \
    for (int q_ = 0; q_ < 4; ++q_)                                                 \
        gload_lds16(xhi + aoff[q_] + ko_, sA + (buf) * 16384 + q_ * 4096 + tid * 8);\
    _Pragma("unroll")                                                              \
    for (int q_ = 0; q_ < 4; ++q_)                                                 \
        gload_lds16(whiT + boff[q_] + ko_, sB + (buf) * 16384 + q_ * 4096 + tid * 8);\
} while (0)

__global__ __launch_bounds__(512, 2) void encode_gemm256(const f16* __restrict__ xhi,
                                                         const f16* __restrict__ whiT,
                                                         const float* __restrict__ b_enc,
                                                         float* __restrict__ preact) {
    extern __shared__ __align__(16) f16 smem[];
    f16* sA = smem;            // 2 * 256 * 64 f16
    f16* sB = smem + 32768;    // 2 * 256 * 64 f16
    const int tid = threadIdx.x;
    const int bid = blockIdx.x;
    const int xcd = bid & 7;
    const int idx = bid >> 3;                        // 0..127
    const int n0 = (xcd * 8 + (idx & 7)) * BN;       // XCD-local 8 n-panels
    const int m0 = (idx >> 3) * BM;                  // 16 m-panels
    const int lane = tid & 63;
    const int wr = (tid >> 6) >> 2;                 // 0..1
    const int wc = (tid >> 6) & 3;                  // 0..3
    const int fr = lane & 15;
    const int fk = lane >> 4;
    // reader slot offsets (f16 units) for ks=0/1: slot (fk+4*ks) ^ (fr&7)
    const int sxk0 = ((fk)     ^ (fr & 7)) * 8;
    const int sxk1 = ((fk + 4) ^ (fr & 7)) * 8;

    // staging source offsets (f16 units): thread covers rows q*64 + (tid>>3),
    // 16B chunk c = tid&7, source k-slot pre-swizzled by (row&7) = ((tid>>3)&7)
    const int sw = ((tid & 7) ^ ((tid >> 3) & 7)) << 3;
    int aoff[4], boff[4];
#pragma unroll
    for (int q = 0; q < 4; ++q) {
        const int p = q * 64 + (tid >> 3);
        aoff[q] = (m0 + p) * D_IN + sw;
        boff[q] = (n0 + p) * D_IN + sw;
    }

    floatx4 acc[8][4];
    const floatx4 zero = {0.f, 0.f, 0.f, 0.f};
#pragma unroll
    for (int i = 0; i < 8; ++i)
#pragma unroll
        for (int j = 0; j < 4; ++j) acc[i][j] = zero;

    STAGE(0, 0);
    for (int t = 0; t < NKT; ++t) {
        __syncthreads();                 // drains vmcnt(0)+lgkmcnt(0): tile t landed,
                                         // and iter t-1's ds_reads are complete in all waves
        if (t + 1 < NKT) STAGE((t + 1) & 1, t + 1);
        const int bufo = (t & 1) * 16384;
#pragma unroll
        for (int ks = 0; ks < 2; ++ks) {
            const int sx = ks ? sxk1 : sxk0;
            f16x8 af[8], bf[4];
#pragma unroll
            for (int mi = 0; mi < 8; ++mi)
                af[mi] = *(const f16x8*)(sA + bufo + (wr * 128 + mi * 16 + fr) * 64 + sx);
#pragma unroll
            for (int ni = 0; ni < 4; ++ni)
                bf[ni] = *(const f16x8*)(sB + bufo + (wc * 64 + ni * 16 + fr) * 64 + sx);
#pragma unroll
            for (int mi = 0; mi < 8; ++mi)
#pragma unroll
                for (int ni = 0; ni < 4; ++ni)
                    acc[mi][ni] = __builtin_amdgcn_mfma_f32_16x16x32_f16(
                        af[mi], bf[ni], acc[mi][ni], 0, 0, 0);
        }
    }

    // epilogue: C/D col = lane&15, row = (lane>>4)*4 + j; add bias, fp32 store
#pragma unroll
    for (int ni = 0; ni < 4; ++ni) {
        const int col = n0 + wc * 64 + ni * 16 + fr;
        const float bias = b_enc[col];
#pragma unroll
        for (int mi = 0; mi < 8; ++mi) {
            const int row = m0 + wr * 128 + mi * 16 + fk * 4;
            float* p = preact + (size_t)row * H_DIM + col;
#pragma unroll
            for (int j = 0; j < 4; ++j)
                p[(size_t)j * H_DIM] = acc[mi][ni][j] + bias;
        }
    }
}

// ---------------- candidate selection: single-level linear-bin select ----------------
// Suffix scan done with wave shfl (1 barrier) instead of 16-barrier LDS scan.
__global__ __launch_bounds__(256) void topk_approx(const float* __restrict__ preact,
                                                   int* __restrict__ cand,
                                                   int* __restrict__ ccnt) {
    const int row = blockIdx.x;
    const int t   = threadIdx.x;
    const float* pr = preact + (size_t)row * H_DIM;
    float vr[64];
    float m = 0.f;
#pragma unroll
    for (int i = 0; i < 16; ++i) {
        const float4 q = ((const float4*)pr)[t + 256 * i];
        vr[4 * i + 0] = q.x; vr[4 * i + 1] = q.y;
        vr[4 * i + 2] = q.z; vr[4 * i + 3] = q.w;
        m = fmaxf(m, fmaxf(fmaxf(q.x, q.y), fmaxf(q.z, q.w)));
    }
#pragma unroll
    for (int off = 32; off > 0; off >>= 1) m = fmaxf(m, __shfl_down(m, off));

    __shared__ float wmax[4];
    __shared__ unsigned hist[256];
    __shared__ unsigned wsum[4];
    __shared__ unsigned sbin_s, out_cnt;
    if ((t & 63) == 0) wmax[t >> 6] = m;
    hist[t] = 0u;
    if (t == 0) { sbin_s = 0u; out_cnt = 0u; }
    __syncthreads();
    const float M = fmaxf(fmaxf(wmax[0], wmax[1]), fmaxf(wmax[2], wmax[3]));
    int* crow = cand + row * NCAP;

    if (M > 0.f) {
        const float scale = 256.0f / M;
#pragma unroll
        for (int e = 0; e < 64; ++e) {
            const float v = vr[e];
            if (v > 0.f) {
                int b = (int)(v * scale); b = b > 255 ? 255 : b;
                atomicAdd(&hist[b], 1u);
            }
        }
        __syncthreads();
        // suffix (reverse inclusive) scan: wave shfl + 1 barrier
        const unsigned horig = hist[t];
        unsigned sval = horig;
#pragma unroll
        for (int off = 1; off < 64; off <<= 1) {
            const unsigned add = __shfl_down(sval, off);
            if ((t & 63) + off < 64) sval += add;
        }
        if ((t & 63) == 0) wsum[t >> 6] = sval;   // whole-wave suffix total
        __syncthreads();
        for (int w = (t >> 6) + 1; w < 4; ++w) sval += wsum[w];
        const unsigned above = sval - horig;      // suffix strictly after t
        if (sval >= NC && above < NC) sbin_s = (unsigned)t;
        __syncthreads();
        const int sbin = (int)sbin_s;   // 0 if total positives < NC -> collect all
#pragma unroll
        for (int e = 0; e < 64; ++e) {
            const float v = vr[e];
            if (v > 0.f) {
                int b = (int)(v * scale); b = b > 255 ? 255 : b;
                if (b >= sbin) {
                    const unsigned p = atomicAdd(&out_cnt, 1u);
                    if (p < NCAP) crow[p] = 4 * t + 1024 * (e >> 2) + (e & 3);
                }
            }
        }
        __syncthreads();
    }
    if (t == 0) ccnt[row] = (int)(out_cnt < NCAP ? out_cnt : NCAP);
}

// ---------------- exact fp32 refinement of candidates + hidden write ----------------
__global__ __launch_bounds__(256) void refine_kernel(const float* __restrict__ x,
                                                     const f16* __restrict__ whiT,
                                                     const f16* __restrict__ wloT,
                                                     const float* __restrict__ b_enc,
                                                     const int* __restrict__ cand,
                                                     const int* __restrict__ ccnt,
                                                     float* __restrict__ hidden,
                                                     float* __restrict__ topv,
                                                     int* __restrict__ topi) {
    const int row  = blockIdx.x;
    const int t    = threadIdx.x;
    const int lane = t & 63;
    const int wave = t >> 6;
    __shared__ float xr[D_IN];
    __shared__ float cv[NCAP];
    __shared__ int   ci[NCAP];
    __shared__ float selv[TOPK_N];
    __shared__ int   seli[TOPK_N];

    const int cnt = ccnt[row];
    if (t < NCAP) ci[t] = (t < cnt) ? cand[row * NCAP + t] : -1;
    if (t < TOPK_N) { selv[t] = -3.0e38f; seli[t] = -1; }
#pragma unroll
    for (int j = 0; j < 3; ++j)
        xr[t + 256 * j] = x[(size_t)row * D_IN + t + 256 * j];
    __syncthreads();

    for (int c = wave; c < cnt; c += 4) {
        const int n = ci[c];
        float sum = 0.f;
        const f16* wh = whiT + (size_t)n * D_IN;
        const f16* wl = wloT + (size_t)n * D_IN;
#pragma unroll
        for (int j = 0; j < 6; ++j) {
            const int k = 2 * lane + 128 * j;
            const f16x2 h2 = *(const f16x2*)&wh[k];
            const f16x2 l2 = *(const f16x2*)&wl[k];
            const float2 x2 = *(const float2*)&xr[k];
            sum += x2.x * ((float)h2[0] + (float)l2[0]);
            sum += x2.y * ((float)h2[1] + (float)l2[1]);
        }
#pragma unroll
        for (int off = 32; off > 0; off >>= 1) sum += __shfl_down(sum, off);
        if (lane == 0) cv[c] = sum + b_enc[n];
    }
    __syncthreads();

    if (t < cnt) {
        const float vi = cv[t];
        const int   ii = ci[t];
        int rank = 0;
        for (int j = 0; j < cnt; ++j) {
            const float vj = cv[j];
            rank += (vj > vi) || (vj == vi && ci[j] < ii);
        }
        if (rank < TOPK_N) { selv[rank] = vi; seli[rank] = ii; }
    }
    __syncthreads();

    float* hrow = hidden + (size_t)row * H_DIM;
    const float4 z = {0.f, 0.f, 0.f, 0.f};
#pragma unroll
    for (int i = 0; i < 16; ++i) ((float4*)hrow)[t + 256 * i] = z;
    __syncthreads();
    if (t < TOPK_N) {
        const int n = seli[t];
        float v = selv[t];
        v = (n >= 0) ? fmaxf(v, 0.f) : 0.f;
        topv[row * TOPK_N + t] = v;
        topi[row * TOPK_N + t] = (n >= 0) ? n : 0;
        if (v > 0.f) hrow[n] = v;
    }
}

// ---------------- sparse decode: out = relu(hidden_sparse @ W_dec + b_dec) ----------------
__global__ __launch_bounds__(256) void decode_kernel(const float* __restrict__ topv,
                                                     const int* __restrict__ topi,
                                                     const float* __restrict__ Wdec,
                                                     const float* __restrict__ bdec,
                                                     float* __restrict__ out) {
    const int row = blockIdx.x;
    const int t   = threadIdx.x;
    __shared__ float sv[TOPK_N];
    __shared__ int   si[TOPK_N];
    if (t < TOPK_N) { sv[t] = topv[row * TOPK_N + t]; si[t] = topi[row * TOPK_N + t]; }
    __syncthreads();
    float a0 = 0.f, a1 = 0.f, a2 = 0.f;
#pragma unroll 4
    for (int j = 0; j < TOPK_N; ++j) {
        const float v = sv[j];
        const float* wr = Wdec + (size_t)si[j] * D_IN;
        a0 += v * wr[t];
        a1 += v * wr[t + 256];
        a2 += v * wr[t + 512];
    }
    float* orow = out + (size_t)row * D_IN;
    orow[t]       = fmaxf(a0 + bdec[t], 0.f);
    orow[t + 256] = fmaxf(a1 + bdec[t + 256], 0.f);
    orow[t + 512] = fmaxf(a2 + bdec[t + 512], 0.f);
}

extern "C" void kernel_launch(void* const* d_in, const int* in_sizes, int n_in,
                              void* d_out, int out_size, void* d_ws, size_t ws_size,
                              hipStream_t stream) {
    const float* x     = (const float*)d_in[0];
    const float* W_enc = (const float*)d_in[1];
    const float* b_enc = (const float*)d_in[2];
    const float* W_dec = (const float*)d_in[3];
    const float* b_dec = (const float*)d_in[4];

    float* out    = (float*)d_out;
    float* hidden = out + (size_t)B_ROWS * D_IN;
    float* preact = hidden + (size_t)B_ROWS * H_DIM;

    uint8_t* ws = (uint8_t*)d_ws;
    size_t off = 0;
    f16* xhi  = (f16*)(ws + off); off += (size_t)B_ROWS * D_IN * 2;
    f16* whiT = (f16*)(ws + off); off += (size_t)H_DIM * D_IN * 2;
    f16* wloT = (f16*)(ws + off); off += (size_t)H_DIM * D_IN * 2;
    int*   cand = (int*)(ws + off);  off += (size_t)B_ROWS * NCAP * 4;
    int*   ccnt = (int*)(ws + off);  off += (size_t)B_ROWS * 4;
    float* topv = (float*)(ws + off); off += (size_t)B_ROWS * TOPK_N * 4;
    int*   topi = (int*)(ws + off);  off += (size_t)B_ROWS * TOPK_N * 4;
    if (off > ws_size) return;  // insufficient workspace -> fail visibly

    hipFuncSetAttribute(reinterpret_cast<const void*>(encode_gemm256),
                        hipFuncAttributeMaxDynamicSharedMemorySize, 131072);

    split_x<<<(B_ROWS * D_IN / 4) / 256, 256, 0, stream>>>(x, xhi);
    dim3 gw(D_IN / 64, H_DIM / 64);
    split_transpose_w<<<gw, 256, 0, stream>>>(W_enc, whiT, wloT);
    encode_gemm256<<<(B_ROWS / BM) * (H_DIM / BN), 512, 131072, stream>>>(xhi, whiT, b_enc, preact);
    topk_approx<<<B_ROWS, 256, 0, stream>>>(preact, cand, ccnt);
    refine_kernel<<<B_ROWS, 256, 0, stream>>>(x, whiT, wloT, b_enc, cand, ccnt, hidden, topv, topi);
    decode_kernel<<<B_ROWS, 256, 0, stream>>>(topv, topi, W_dec, b_dec, out);
}

// Round 9
// 393.288 us; speedup vs baseline: 1.0635x; 1.0326x over previous
//
#include <hip/hip_runtime.h>
#include <stdint.h>

typedef _Float16 f16;
typedef _Float16 f16x4 __attribute__((ext_vector_type(4)));
typedef _Float16 f16x8 __attribute__((ext_vector_type(8)));
typedef float floatx4 __attribute__((ext_vector_type(4)));

#define B_ROWS 4096
#define D_IN   768
#define H_DIM  16384
#define TOPK_N 32
#define NC     40    // target candidate count (superset of exact top-32)
#define NCAP   192   // hard cap on candidates per row

#define BM 256
#define BN 256
#define BK 64
#define NKT (D_IN / BK)   // 12 K-tiles

typedef __attribute__((address_space(1))) const unsigned int g_uint;
typedef __attribute__((address_space(3))) unsigned int l_uint;

__device__ __forceinline__ void gload_lds16(const void* g, void* l) {
    __builtin_amdgcn_global_load_lds((g_uint*)(uintptr_t)g,
                                     (l_uint*)(uint32_t)(uintptr_t)l,
                                     16, 0, 0);
}

// ---------------- split x -> f16 ----------------
__global__ __launch_bounds__(256) void split_x(const float* __restrict__ x,
                                               f16* __restrict__ xhi) {
    const int i = blockIdx.x * 256 + threadIdx.x;
    const float4 q = ((const float4*)x)[i];
    f16x4 h;
    h[0] = (f16)q.x; h[1] = (f16)q.y; h[2] = (f16)q.z; h[3] = (f16)q.w;
    ((f16x4*)xhi)[i] = h;
}

// ---------------- transpose + hi/lo split of W_enc ----------------
// W [768][16384] f32  ->  whiT/wloT [16384][768] f16 (k contiguous)
__global__ __launch_bounds__(256) void split_transpose_w(const float* __restrict__ W,
                                                         f16* __restrict__ whiT,
                                                         f16* __restrict__ wloT) {
    __shared__ float tile[64][65];
    const int kb = blockIdx.x;      // 0..11
    const int nb = blockIdx.y;      // 0..255
    const int t  = threadIdx.x;
    const int col = t & 63;
    const int r4  = t >> 6;
#pragma unroll
    for (int p = 0; p < 16; ++p) {
        const int kr = p * 4 + r4;
        tile[kr][col] = W[(size_t)(kb * 64 + kr) * H_DIM + nb * 64 + col];
    }
    __syncthreads();
    const int n  = t >> 2;
    const int kq = (t & 3) * 16;
    f16x8 h0, h1, l0, l1;
#pragma unroll
    for (int j = 0; j < 8; ++j) {
        const float v0 = tile[kq + j][n];
        const f16 ha = (f16)v0; h0[j] = ha; l0[j] = (f16)(v0 - (float)ha);
        const float v1 = tile[kq + 8 + j][n];
        const f16 hb = (f16)v1; h1[j] = hb; l1[j] = (f16)(v1 - (float)hb);
    }
    const size_t base = (size_t)(nb * 64 + n) * D_IN + kb * 64 + kq;
    *(f16x8*)&whiT[base]     = h0;
    *(f16x8*)&whiT[base + 8] = h1;
    *(f16x8*)&wloT[base]     = l0;
    *(f16x8*)&wloT[base + 8] = l1;
}

// ---------------- encode GEMM: 256x256, BK=64, classic dbuf (R5-proven, verbatim) ----
#define STAGE(buf, kt) do {                                                        \
    const int ko_ = (kt) * BK;                                                     \
    _Pragma("unroll")                                                              \
    for (int q_ = 0; q_ < 4; ++q_)                                                 \
        gload_lds16(xhi + aoff[q_] + ko_, sA + (buf) * 16384 + q_ * 4096 + tid * 8);\
    _Pragma("unroll")                                                              \
    for (int q_ = 0; q_ < 4; ++q_)                                                 \
        gload_lds16(whiT + boff[q_] + ko_, sB + (buf) * 16384 + q_ * 4096 + tid * 8);\
} while (0)

__global__ __launch_bounds__(512, 2) void encode_gemm256(const f16* __restrict__ xhi,
                                                         const f16* __restrict__ whiT,
                                                         const float* __restrict__ b_enc,
                                                         float* __restrict__ preact) {
    extern __shared__ __align__(16) f16 smem[];
    f16* sA = smem;            // 2 * 256 * 64 f16
    f16* sB = smem + 32768;    // 2 * 256 * 64 f16
    const int tid = threadIdx.x;
    const int bid = blockIdx.x;
    const int swz = (bid & 7) * 128 + (bid >> 3);   // XCD swizzle, nwg=1024 % 8 == 0
    const int m0 = (swz >> 6) * BM;                 // 16 m-blocks
    const int n0 = (swz & 63) * BN;                 // 64 n-blocks
    const int lane = tid & 63;
    const int wr = (tid >> 6) >> 2;                 // 0..1
    const int wc = (tid >> 6) & 3;                  // 0..3
    const int fr = lane & 15;
    const int fk = lane >> 4;
    const int sxk0 = ((fk)     ^ (fr & 7)) * 8;
    const int sxk1 = ((fk + 4) ^ (fr & 7)) * 8;

    const int sw = ((tid & 7) ^ ((tid >> 3) & 7)) << 3;
    int aoff[4], boff[4];
#pragma unroll
    for (int q = 0; q < 4; ++q) {
        const int p = q * 64 + (tid >> 3);
        aoff[q] = (m0 + p) * D_IN + sw;
        boff[q] = (n0 + p) * D_IN + sw;
    }

    floatx4 acc[8][4];
    const floatx4 zero = {0.f, 0.f, 0.f, 0.f};
#pragma unroll
    for (int i = 0; i < 8; ++i)
#pragma unroll
        for (int j = 0; j < 4; ++j) acc[i][j] = zero;

    STAGE(0, 0);
    for (int t = 0; t < NKT; ++t) {
        __syncthreads();
        if (t + 1 < NKT) STAGE((t + 1) & 1, t + 1);
        const int bufo = (t & 1) * 16384;
#pragma unroll
        for (int ks = 0; ks < 2; ++ks) {
            const int sx = ks ? sxk1 : sxk0;
            f16x8 af[8], bf[4];
#pragma unroll
            for (int mi = 0; mi < 8; ++mi)
                af[mi] = *(const f16x8*)(sA + bufo + (wr * 128 + mi * 16 + fr) * 64 + sx);
#pragma unroll
            for (int ni = 0; ni < 4; ++ni)
                bf[ni] = *(const f16x8*)(sB + bufo + (wc * 64 + ni * 16 + fr) * 64 + sx);
#pragma unroll
            for (int mi = 0; mi < 8; ++mi)
#pragma unroll
                for (int ni = 0; ni < 4; ++ni)
                    acc[mi][ni] = __builtin_amdgcn_mfma_f32_16x16x32_f16(
                        af[mi], bf[ni], acc[mi][ni], 0, 0, 0);
        }
    }

#pragma unroll
    for (int ni = 0; ni < 4; ++ni) {
        const int col = n0 + wc * 64 + ni * 16 + fr;
        const float bias = b_enc[col];
#pragma unroll
        for (int mi = 0; mi < 8; ++mi) {
            const int row = m0 + wr * 128 + mi * 16 + fk * 4;
            float* p = preact + (size_t)row * H_DIM + col;
#pragma unroll
            for (int j = 0; j < 4; ++j)
                p[(size_t)j * H_DIM] = acc[mi][ni][j] + bias;
        }
    }
}

// ---------------- fused tail: topk-select + exact refine + hidden write + decode ----
// One block per row; stages are the R5-proven kernels verbatim, joined by
// __syncthreads, with cand/cv/sel kept in LDS (no global round-trips).
__global__ __launch_bounds__(256) void fused_tail(const float* __restrict__ x,
                                                  const float* __restrict__ preact,
                                                  const f16* __restrict__ whiT,
                                                  const f16* __restrict__ wloT,
                                                  const float* __restrict__ b_enc,
                                                  const float* __restrict__ Wdec,
                                                  const float* __restrict__ bdec,
                                                  float* __restrict__ hidden,
                                                  float* __restrict__ out) {
    const int row  = blockIdx.x;
    const int t    = threadIdx.x;
    const int lane = t & 63;
    const int wave = t >> 6;

    __shared__ float xr[D_IN];
    __shared__ float cv[NCAP];
    __shared__ int   ci[NCAP];
    __shared__ float selv[TOPK_N];
    __shared__ int   seli[TOPK_N];
    __shared__ float wmax[4];
    __shared__ unsigned hist[256];
    __shared__ unsigned sbin_s, out_cnt;

    // ---- stage 0: x row + init (overlaps with preact reads below) ----
#pragma unroll
    for (int j = 0; j < 3; ++j)
        xr[t + 256 * j] = x[(size_t)row * D_IN + t + 256 * j];
    if (t < TOPK_N) { selv[t] = -3.0e38f; seli[t] = -1; }

    // ---- stage 1: load preact row, per-row max (R5 topk code) ----
    const float* pr = preact + (size_t)row * H_DIM;
    float vr[64];
    float m = 0.f;
#pragma unroll
    for (int i = 0; i < 16; ++i) {
        const float4 q = ((const float4*)pr)[t + 256 * i];
        vr[4 * i + 0] = q.x; vr[4 * i + 1] = q.y;
        vr[4 * i + 2] = q.z; vr[4 * i + 3] = q.w;
        m = fmaxf(m, fmaxf(fmaxf(q.x, q.y), fmaxf(q.z, q.w)));
    }
#pragma unroll
    for (int off = 32; off > 0; off >>= 1) m = fmaxf(m, __shfl_down(m, off));

    if ((t & 63) == 0) wmax[t >> 6] = m;
    hist[t] = 0u;
    if (t == 0) { sbin_s = 0u; out_cnt = 0u; }
    __syncthreads();
    const float M = fmaxf(fmaxf(wmax[0], wmax[1]), fmaxf(wmax[2], wmax[3]));

    if (M > 0.f) {   // uniform branch per block
        const float scale = 256.0f / M;
#pragma unroll
        for (int e = 0; e < 64; ++e) {
            const float v = vr[e];
            if (v > 0.f) {
                int b = (int)(v * scale); b = b > 255 ? 255 : b;
                atomicAdd(&hist[b], 1u);
            }
        }
        __syncthreads();
        // suffix (reverse inclusive) scan over 256 bins (R5 LDS scan)
        unsigned sval = hist[t];
        for (int off = 1; off < 256; off <<= 1) {
            const unsigned add = (t + off < 256) ? hist[t + off] : 0u;
            __syncthreads();
            sval += add;
            hist[t] = sval;
            __syncthreads();
        }
        const unsigned above = (t < 255) ? hist[t + 1] : 0u;
        if (sval >= NC && above < NC) sbin_s = (unsigned)t;
        __syncthreads();
        const int sbin = (int)sbin_s;
#pragma unroll
        for (int e = 0; e < 64; ++e) {
            const float v = vr[e];
            if (v > 0.f) {
                int b = (int)(v * scale); b = b > 255 ? 255 : b;
                if (b >= sbin) {
                    const unsigned p = atomicAdd(&out_cnt, 1u);
                    if (p < NCAP) ci[p] = 4 * t + 1024 * (e >> 2) + (e & 3);
                }
            }
        }
    }
    __syncthreads();
    const int cnt = (M > 0.f) ? (int)(out_cnt < NCAP ? out_cnt : NCAP) : 0;

    // ---- stage 2: exact fp32 refine of candidates (R5 refine code) ----
    for (int c = wave; c < cnt; c += 4) {
        const int n = ci[c];
        float sum = 0.f;
        const f16* wh = whiT + (size_t)n * D_IN;
        const f16* wl = wloT + (size_t)n * D_IN;
#pragma unroll
        for (int j = 0; j < 12; ++j) {
            const int k = lane + 64 * j;
            sum += xr[k] * ((float)wh[k] + (float)wl[k]);
        }
#pragma unroll
        for (int off = 32; off > 0; off >>= 1) sum += __shfl_down(sum, off);
        if (lane == 0) cv[c] = sum + b_enc[n];
    }
    __syncthreads();

    if (t < cnt) {
        const float vi = cv[t];
        const int   ii = ci[t];
        int rank = 0;
        for (int j = 0; j < cnt; ++j) {
            const float vj = cv[j];
            rank += (vj > vi) || (vj == vi && ci[j] < ii);
        }
        if (rank < TOPK_N) { selv[rank] = vi; seli[rank] = ii; }
    }
    __syncthreads();

    // ---- stage 3: zero hidden row, then scatter top-32 ----
    float* hrow = hidden + (size_t)row * H_DIM;
    const float4 z = {0.f, 0.f, 0.f, 0.f};
#pragma unroll
    for (int i = 0; i < 16; ++i) ((float4*)hrow)[t + 256 * i] = z;
    __syncthreads();
    if (t < TOPK_N) {
        const int n = seli[t];
        float v = selv[t];
        v = (n >= 0) ? fmaxf(v, 0.f) : 0.f;
        if (v > 0.f) hrow[n] = v;
    }

    // ---- stage 4: decode (R5 decode code, sel in LDS) ----
    float a0 = 0.f, a1 = 0.f, a2 = 0.f;
#pragma unroll 4
    for (int j = 0; j < TOPK_N; ++j) {
        const int n = seli[j];
        const float v = (n >= 0) ? fmaxf(selv[j], 0.f) : 0.f;
        const float* wr = Wdec + (size_t)(n >= 0 ? n : 0) * D_IN;
        a0 += v * wr[t];
        a1 += v * wr[t + 256];
        a2 += v * wr[t + 512];
    }
    float* orow = out + (size_t)row * D_IN;
    orow[t]       = fmaxf(a0 + bdec[t], 0.f);
    orow[t + 256] = fmaxf(a1 + bdec[t + 256], 0.f);
    orow[t + 512] = fmaxf(a2 + bdec[t + 512], 0.f);
}

extern "C" void kernel_launch(void* const* d_in, const int* in_sizes, int n_in,
                              void* d_out, int out_size, void* d_ws, size_t ws_size,
                              hipStream_t stream) {
    const float* x     = (const float*)d_in[0];
    const float* W_enc = (const float*)d_in[1];
    const float* b_enc = (const float*)d_in[2];
    const float* W_dec = (const float*)d_in[3];
    const float* b_dec = (const float*)d_in[4];

    float* out    = (float*)d_out;
    float* hidden = out + (size_t)B_ROWS * D_IN;
    float* preact = hidden + (size_t)B_ROWS * H_DIM;

    uint8_t* ws = (uint8_t*)d_ws;
    size_t off = 0;
    f16* xhi  = (f16*)(ws + off); off += (size_t)B_ROWS * D_IN * 2;
    f16* whiT = (f16*)(ws + off); off += (size_t)H_DIM * D_IN * 2;
    f16* wloT = (f16*)(ws + off); off += (size_t)H_DIM * D_IN * 2;
    if (off > ws_size) return;  // insufficient workspace -> fail visibly

    hipFuncSetAttribute(reinterpret_cast<const void*>(encode_gemm256),
                        hipFuncAttributeMaxDynamicSharedMemorySize, 131072);

    split_x<<<(B_ROWS * D_IN / 4) / 256, 256, 0, stream>>>(x, xhi);
    dim3 gw(D_IN / 64, H_DIM / 64);
    split_transpose_w<<<gw, 256, 0, stream>>>(W_enc, whiT, wloT);
    encode_gemm256<<<(B_ROWS / BM) * (H_DIM / BN), 512, 131072, stream>>>(xhi, whiT, b_enc, preact);
    fused_tail<<<B_ROWS, 256, 0, stream>>>(x, preact, whiT, wloT, b_enc, W_dec, b_dec,
                                           hidden, out);
}